// Round 9
// baseline (143.738 us; speedup 1.0000x reference)
//
#include <hip/hip_runtime.h>

// ============================================================================
// Piecewise-constant LUT, v4: NO per-element scan path.
//
// Reference per element (fp32; chain validated bit-exact R0-R7):
//   a = |x|; v = a; z = 0; acc = 0
//   for t: v = fmaf(-z,h[t],v); z = (v > T[t]); acc = fmaf(z,d[t],acc)
//   out = acc * sign(x)
//
// Endpoint-mask rule (validated R6/R7, absmax 0): equal 16-bit predicate
// masks at the endpoints of a bit-space interval => mask constant on it.
// Value depends only on the mask => exact per-segment value.
//
// 4096 bins x 9216 ULPs over [0.0625, 1.5). Clean bin -> value inline.
// Bin with 1..12 transitions -> record {c bps, c+1 values} in a packed pool
// (atomicAdd allocation; order irrelevant). LUT entry = 0x7F800000|c<<19|start.
// Apply: one flat path, short exec-masked loop, NO exact-scan branch.
// Overflow (>12 transitions/bin or pool > 2048 words or non-uniform lo/hi
// region) -> global flag -> whole apply kernel switches (wave-uniformly) to
// direct scalar scan. Never mixes per-element.
// ============================================================================

#define BIN_B0 0x3D800000u   // bits(0.0625)
#define BIN_B1 0x3FC00000u   // bits(1.5)
#define BIN_RANGE 0x02400000u
#define NBIN 4096
#define CMAX 12
#define BP_CAP 2048          // words in breakpoint/value pool (8 KB)

#define W_CNT 0
#define W_FLAG 1
#define W_LO 2
#define W_HI 3
#define W_LUT 4
#define W_BP (W_LUT + NBIN)
#define WS_WORDS (W_BP + BP_CAP)   // 6148 words = 24.6 KB

__device__ __forceinline__ int predmask16(float a, const float* __restrict__ hh,
                                          const float* __restrict__ TT) {
    float v = a, z = 0.0f;
    int m = 0;
#pragma unroll
    for (int k = 0; k < 16; ++k) {
        v = fmaf(-z, hh[k], v);
        int zb = (v > TT[k]) ? 1 : 0;
        z = zb ? 1.0f : 0.0f;
        m |= zb << k;
    }
    return m;
}

__device__ __forceinline__ unsigned int valbits(int m, const float* __restrict__ dd) {
    float acc = 0.0f;
#pragma unroll
    for (int k = 0; k < 16; ++k)
        acc = ((m >> k) & 1) ? (acc + dd[k]) : acc;  // fl(acc+d) == fmaf(1,d,acc)
    return __float_as_uint(acc);
}

__device__ __forceinline__ float scan_exact(unsigned int ab, const float* __restrict__ hh,
                                            const float* __restrict__ dd,
                                            const float* __restrict__ TT) {
    float v = __uint_as_float(ab), z = 0.0f, acc = 0.0f;
#pragma unroll
    for (int k = 0; k < 16; ++k) {
        v = fmaf(-z, hh[k], v);
        z = (v > TT[k]) ? 1.0f : 0.0f;
        acc = fmaf(z, dd[k], acc);
    }
    return acc;
}

// ------------------------------------------------------------------ K0: init
__global__ void snn_init(unsigned int* __restrict__ ws) {
    if (threadIdx.x == 0) { ws[W_CNT] = 0u; ws[W_FLAG] = 0u; }
}

// ----------------------------------------------------------------- K1: build
__global__ __launch_bounds__(256) void snn_build(
    const float* __restrict__ h, const float* __restrict__ d,
    const float* __restrict__ T, unsigned int* __restrict__ ws) {
    const int u = blockIdx.x * 256 + threadIdx.x;
    if (u >= NBIN + 2) return;
    float hh[16], dd[16], TT[16];
#pragma unroll
    for (int k = 0; k < 16; ++k) { hh[k] = h[k]; dd[k] = d[k]; TT[k] = T[k]; }

    if (u == NBIN) {  // low region [0, B0)
        int mA = predmask16(__uint_as_float(0u), hh, TT);
        int mB = predmask16(__uint_as_float(BIN_B0 - 1u), hh, TT);
        if (mA == mB) ws[W_LO] = valbits(mA, dd);
        else { ws[W_LO] = 0u; atomicOr(&ws[W_FLAG], 1u); }
        return;
    }
    if (u == NBIN + 1) {  // high region [B1, max finite]
        int mA = predmask16(__uint_as_float(BIN_B1), hh, TT);
        int mB = predmask16(__uint_as_float(0x7F7FFFFFu), hh, TT);
        if (mA == mB) ws[W_HI] = valbits(mA, dd);
        else { ws[W_HI] = 0u; atomicOr(&ws[W_FLAG], 1u); }
        return;
    }

    const unsigned int Lb = BIN_B0 + (unsigned int)u * 9216u;
    const unsigned int Hb = Lb + 9215u;
    const int mL = predmask16(__uint_as_float(Lb), hh, TT);
    const int mH = predmask16(__uint_as_float(Hb), hh, TT);
    if (mL == mH) { ws[W_LUT + u] = valbits(mL, dd); return; }

    // Enumerate ALL transitions in (Lb, Hb]; invariant: mask(anchor) == cur.
    unsigned int bp[CMAX];
    int vm[CMAX + 1];
    vm[0] = mL;
    int cnt = 0, cur = mL;
    unsigned int anchor = Lb;
    bool bad = false;
    while (cur != mH) {
        if (cnt == CMAX) { bad = true; break; }
        unsigned int lo = anchor, hi = Hb;
        int mhi = mH;
        while (hi - lo > 1u) {
            unsigned int mid = lo + ((hi - lo) >> 1);
            int mm = predmask16(__uint_as_float(mid), hh, TT);
            if (mm == cur) lo = mid; else { hi = mid; mhi = mm; }
        }
        bp[cnt] = hi;        // first point whose mask != cur
        vm[cnt + 1] = mhi;   // its mask
        ++cnt;
        cur = mhi;
        anchor = hi;
    }
    if (bad) { atomicOr(&ws[W_FLAG], 1u); ws[W_LUT + u] = 0u; return; }

    const unsigned int need = 2u * (unsigned int)cnt + 1u;
    const unsigned int start = atomicAdd(&ws[W_CNT], need);
    if (start + need > BP_CAP) { atomicOr(&ws[W_FLAG], 1u); ws[W_LUT + u] = 0u; return; }
    for (int k = 0; k < cnt; ++k) ws[W_BP + start + k] = bp[k];
    for (int j = 0; j <= cnt; ++j)
        ws[W_BP + start + cnt + j] = valbits(vm[j], dd);
    ws[W_LUT + u] = 0x7F800000u | ((unsigned int)cnt << 19) | start;
}

// ----------------------------------------------------------------- K2: apply
__device__ __forceinline__ float lut_elem(float xe,
                                          const unsigned int* __restrict__ lutS,
                                          const unsigned int* __restrict__ bpS,
                                          unsigned int lo_e, unsigned int hi_e) {
    const unsigned int u = __float_as_uint(xe);
    const unsigned int sb = u & 0x80000000u;
    const unsigned int ab = u & 0x7FFFFFFFu;
    unsigned int t = ab - BIN_B0;                    // wraps if ab < B0
    t = (t > BIN_RANGE - 1u) ? (BIN_RANGE - 1u) : t; // clamp wrap / high
    const unsigned int bin = ((t >> 10) * 58255u) >> 19;  // exact floor(/9216)
    unsigned int eb = lutS[bin];
    eb = (ab < BIN_B0) ? lo_e : eb;
    eb = (ab >= BIN_B1) ? hi_e : eb;
    if ((eb & 0x7F800000u) == 0x7F800000u) {  // multi-segment bin record
        const unsigned int s = eb & 0x7FFFFu;
        const unsigned int c = (eb >> 19) & 0xFu;
        unsigned int j = 0;
        for (unsigned int k = 0; k < c; ++k)
            j += (ab >= bpS[s + k]) ? 1u : 0u;
        eb = bpS[s + c + j];
    }
    const float r = __uint_as_float(eb ^ sb);
    return (xe == 0.0f) ? 0.0f : r;
}

__global__ __launch_bounds__(256) void snn_apply(
    const float* __restrict__ x, const float* __restrict__ h,
    const float* __restrict__ d, const float* __restrict__ T,
    float* __restrict__ out, const unsigned int* __restrict__ ws,
    int n8, int n4, int n) {
    __shared__ unsigned int lutS[NBIN];   // 16 KB
    __shared__ unsigned int bpS[BP_CAP];  // 8 KB
    const int tid = threadIdx.x;

    for (int i = tid; i < NBIN; i += 256) lutS[i] = ws[W_LUT + i];
    for (int i = tid; i < BP_CAP; i += 256) bpS[i] = ws[W_BP + i];
    const unsigned int flag = ws[W_FLAG];
    const unsigned int lo_e = ws[W_LO];
    const unsigned int hi_e = ws[W_HI];
    __syncthreads();

    const float4* __restrict__ x4 = reinterpret_cast<const float4*>(x);
    float4* __restrict__ o4 = reinterpret_cast<float4*>(out);
    const int gtid = blockIdx.x * blockDim.x + tid;
    const int nt = gridDim.x * blockDim.x;

    if (flag == 0u) {  // ---- LUT path (expected) ----
#define APPLY4(vv)                                                             \
        {                                                                      \
            float4 ov;                                                         \
            ov.x = lut_elem(vv.x, lutS, bpS, lo_e, hi_e);                      \
            ov.y = lut_elem(vv.y, lutS, bpS, lo_e, hi_e);                      \
            ov.z = lut_elem(vv.z, lutS, bpS, lo_e, hi_e);                      \
            ov.w = lut_elem(vv.w, lutS, bpS, lo_e, hi_e);                      \
            vv = ov;                                                           \
        }
        int i = gtid;  // unit = pair of adjacent float4 (R4 skeleton)
        if (i < n8) {
            float4 ca = x4[2 * i], cb = x4[2 * i + 1];
            int nx = i + nt;
            while (nx < n8) {
                float4 pa = x4[2 * nx], pb = x4[2 * nx + 1];
                APPLY4(ca); APPLY4(cb);
                o4[2 * i] = ca; o4[2 * i + 1] = cb;
                ca = pa; cb = pb;
                i = nx; nx += nt;
            }
            APPLY4(ca); APPLY4(cb);
            o4[2 * i] = ca; o4[2 * i + 1] = cb;
        }
        for (int j = n8 * 2 + gtid; j < n4; j += nt) {
            float4 v = x4[j];
            APPLY4(v);
            o4[j] = v;
        }
        for (int j = n4 * 4 + gtid; j < n; j += nt)
            out[j] = lut_elem(x[j], lutS, bpS, lo_e, hi_e);
#undef APPLY4
    } else {  // ---- wave-uniform fallback: direct scan (correct always) ----
        float hh[16], dd[16], TT[16];
#pragma unroll
        for (int k = 0; k < 16; ++k) { hh[k] = h[k]; dd[k] = d[k]; TT[k] = T[k]; }
        for (int j = gtid; j < n4; j += nt) {
            float4 v = x4[j], ov;
            float* pi = &v.x;
            float* po = &ov.x;
#pragma unroll
            for (int e = 0; e < 4; ++e) {
                float xe = pi[e];
                float acc = scan_exact(__float_as_uint(xe) & 0x7FFFFFFFu, hh, dd, TT);
                unsigned int rb =
                    __float_as_uint(acc) ^ (__float_as_uint(xe) & 0x80000000u);
                po[e] = (xe == 0.0f) ? 0.0f : __uint_as_float(rb);
            }
            o4[j] = ov;
        }
        for (int j = n4 * 4 + gtid; j < n; j += nt) {
            float xe = x[j];
            float acc = scan_exact(__float_as_uint(xe) & 0x7FFFFFFFu, hh, dd, TT);
            unsigned int rb = __float_as_uint(acc) ^ (__float_as_uint(xe) & 0x80000000u);
            out[j] = (xe == 0.0f) ? 0.0f : __uint_as_float(rb);
        }
    }
}

// -------------------------------------------- direct fallback (ws too small)
__global__ __launch_bounds__(256) void snn_direct(
    const float* __restrict__ x, const float* __restrict__ h,
    const float* __restrict__ d, const float* __restrict__ T,
    float* __restrict__ out, int n4, int n) {
    float hh[16], dd[16], TT[16];
#pragma unroll
    for (int k = 0; k < 16; ++k) { hh[k] = h[k]; dd[k] = d[k]; TT[k] = T[k]; }
    const float4* __restrict__ x4 = reinterpret_cast<const float4*>(x);
    float4* __restrict__ o4 = reinterpret_cast<float4*>(out);
    const int gtid = blockIdx.x * blockDim.x + threadIdx.x;
    const int nt = gridDim.x * blockDim.x;
    for (int i = gtid; i < n4; i += nt) {
        float4 v = x4[i], ov;
        float* pi = &v.x;
        float* po = &ov.x;
#pragma unroll
        for (int e = 0; e < 4; ++e) {
            float xe = pi[e];
            float acc = scan_exact(__float_as_uint(xe) & 0x7FFFFFFFu, hh, dd, TT);
            unsigned int rb =
                __float_as_uint(acc) ^ (__float_as_uint(xe) & 0x80000000u);
            po[e] = (xe == 0.0f) ? 0.0f : __uint_as_float(rb);
        }
        o4[i] = ov;
    }
    for (int j = n4 * 4 + gtid; j < n; j += nt) {
        float xe = x[j];
        float acc = scan_exact(__float_as_uint(xe) & 0x7FFFFFFFu, hh, dd, TT);
        unsigned int rb = __float_as_uint(acc) ^ (__float_as_uint(xe) & 0x80000000u);
        out[j] = (xe == 0.0f) ? 0.0f : __uint_as_float(rb);
    }
}

extern "C" void kernel_launch(void* const* d_in, const int* in_sizes, int n_in,
                              void* d_out, int out_size, void* d_ws, size_t ws_size,
                              hipStream_t stream) {
    const float* x = (const float*)d_in[0];
    const float* h = (const float*)d_in[1];
    const float* d = (const float*)d_in[2];
    const float* T = (const float*)d_in[3];
    float* out = (float*)d_out;

    const int n = in_sizes[0];
    const int n4 = n / 4;
    const int n8 = n / 8;

    if (ws_size < (size_t)WS_WORDS * 4) {
        int grid = 2048;
        const int needed = (n4 + 255) / 256;
        if (grid > needed) grid = needed > 0 ? needed : 1;
        snn_direct<<<grid, 256, 0, stream>>>(x, h, d, T, out, n4, n);
        return;
    }

    unsigned int* ws = (unsigned int*)d_ws;
    snn_init<<<1, 64, 0, stream>>>(ws);
    snn_build<<<(NBIN + 2 + 255) / 256, 256, 0, stream>>>(h, d, T, ws);

    // 24 KB LDS/block -> 6 blocks/CU -> 1536 blocks fills the chip.
    int grid = 1536;
    const int needed = (n8 + 255) / 256;
    if (grid > needed) grid = needed > 0 ? needed : 1;
    snn_apply<<<grid, 256, 0, stream>>>(x, h, d, T, out, ws, n8, n4, n);
}